// Round 9
// baseline (267.231 us; speedup 1.0000x reference)
//
#include <hip/hip_runtime.h>
#include <hip/hip_bf16.h>

#define D 128
#define SCAN_BLK 256
#define SCAN_VPT 4
#define SCAN_TILE (SCAN_BLK * SCAN_VPT)   // 1024 nodes per scan block

typedef __attribute__((ext_vector_type(8))) short short8;   // 8 bf16 = 4 VGPR
typedef __attribute__((ext_vector_type(4))) float f32x4;    // MFMA C/D frag

static __device__ __forceinline__ short f2bs(float f) {
  __hip_bfloat16 b = __float2bfloat16(f);
  return *reinterpret_cast<short*>(&b);
}

// ---------------------------------------------------------------------------
// prep_w: WTl/WTr = bf16 transpose of Wl/Wr ([n][k] layout, 16B B-fragments);
// bsum = bl + br. Zeroes deg and the lookback state array.
// ---------------------------------------------------------------------------
__global__ __launch_bounds__(256) void prep_w(
    const float* __restrict__ Wl, const float* __restrict__ Wr,
    const float* __restrict__ bl, const float* __restrict__ br,
    __hip_bfloat16* __restrict__ WTl, __hip_bfloat16* __restrict__ WTr,
    float* __restrict__ bsum, int* __restrict__ deg,
    unsigned long long* __restrict__ state, int n_nodes) {
  const int tid = blockIdx.x * 256 + threadIdx.x;  // grid 128 -> 0..32767
  const int n = (tid >> 7) & 127;
  const int k = tid & 127;
  if (tid < 16384) {
    WTl[n * D + k] = __float2bfloat16(Wl[k * D + n]);
  } else {
    WTr[n * D + k] = __float2bfloat16(Wr[k * D + n]);
  }
  if (tid < 128) bsum[tid] = bl[tid] + br[tid];
  if (tid < 1024) state[tid] = 0ull;
  for (int i = tid; i < n_nodes; i += 32768) deg[i] = 0;
}

// ---------------------------------------------------------------------------
// gemm_wt: WAVE-per-tile, zero LDS, zero barriers.
//   Each wave owns a 16-row tile: 8 independent dwordx4 x-loads issued
//   up-front (fp32 -> bf16 A-frags in regs; the 4 waves of a block read the
//   same rows only via L1), then c-loop over 8 col-tiles: B-frags from
//   L2-hot WT tables + 8 MFMAs (Wl -> h, Wr + bias -> out).
//   No wave waits on any other -> per-CU MLP = sum over all resident waves.
//   Histogram prologue: grid-stride over edges.
// ---------------------------------------------------------------------------
__global__ __launch_bounds__(256) void gemm_wt(
    const float* __restrict__ x, const __hip_bfloat16* __restrict__ WTl,
    const __hip_bfloat16* __restrict__ WTr, const float* __restrict__ bsum,
    __hip_bfloat16* __restrict__ h, float* __restrict__ out,
    const int* __restrict__ edst, int* __restrict__ deg, int n_edges,
    int n_tiles) {
  const int t = threadIdx.x;
  const int gsz = gridDim.x * 256;
  for (int e = blockIdx.x * 256 + t; e < n_edges; e += gsz)
    atomicAdd(&deg[edst[e]], 1);

  const int wtile = blockIdx.x * 4 + (t >> 6);
  if (wtile >= n_tiles) return;
  const int lane = t & 63;
  const int m = lane & 15;
  const int q = lane >> 4;
  const int rowbase = wtile * 16;

  // A: issue all 8 x-loads first (independent), then convert.
  const float* __restrict__ xrow = &x[(size_t)(rowbase + m) * D];
  float4 av[4][2];
#pragma unroll
  for (int ks = 0; ks < 4; ++ks) {
    av[ks][0] = *(const float4*)&xrow[ks * 32 + q * 8];
    av[ks][1] = *(const float4*)&xrow[ks * 32 + q * 8 + 4];
  }
  short8 afrag[4];
#pragma unroll
  for (int ks = 0; ks < 4; ++ks) {
    short8 f;
    f[0] = f2bs(av[ks][0].x); f[1] = f2bs(av[ks][0].y);
    f[2] = f2bs(av[ks][0].z); f[3] = f2bs(av[ks][0].w);
    f[4] = f2bs(av[ks][1].x); f[5] = f2bs(av[ks][1].y);
    f[6] = f2bs(av[ks][1].z); f[7] = f2bs(av[ks][1].w);
    afrag[ks] = f;
  }

  // c-loop over 8 col-tiles of 16; B-frags reloaded per c (L2-hot, 64KB table)
#pragma unroll 2
  for (int c = 0; c < 8; ++c) {
    const int n0 = c * 16;
    short8 bfl[4], bfr[4];
#pragma unroll
    for (int ks = 0; ks < 4; ++ks) {
      bfl[ks] = *(const short8*)&WTl[(n0 + m) * D + ks * 32 + q * 8];
      bfr[ks] = *(const short8*)&WTr[(n0 + m) * D + ks * 32 + q * 8];
    }
    f32x4 aL, aR;
#pragma unroll
    for (int r = 0; r < 4; ++r) { aL[r] = 0.f; aR[r] = 0.f; }
#pragma unroll
    for (int ks = 0; ks < 4; ++ks) {
      aL = __builtin_amdgcn_mfma_f32_16x16x32_bf16(afrag[ks], bfl[ks], aL, 0, 0, 0);
      aR = __builtin_amdgcn_mfma_f32_16x16x32_bf16(afrag[ks], bfr[ks], aR, 0, 0, 0);
    }
    const float bias = bsum[n0 + m];
#pragma unroll
    for (int r = 0; r < 4; ++r) {
      const size_t row = (size_t)(rowbase + q * 4 + r);
      h[row * D + n0 + m] = __float2bfloat16(aL[r]);
      out[row * D + n0 + m] = aR[r] + bias;
    }
  }
}

// ---------------------------------------------------------------------------
// scan_ll: single-pass decoupled-lookback exclusive scan of deg -> offsets
// and pos cursors (proven round 8). 98 blocks <= CU count -> co-resident.
// ---------------------------------------------------------------------------
__global__ __launch_bounds__(SCAN_BLK) void scan_ll(
    int* __restrict__ pos /* deg in, cursors out */, int* __restrict__ offsets,
    unsigned long long* __restrict__ state, int n, int n_edges) {
  __shared__ int sdata[SCAN_BLK];
  __shared__ int s_prefix;
  const int t = threadIdx.x;
  const int b = blockIdx.x;
  const int base = b * SCAN_TILE + t * SCAN_VPT;

  int v[SCAN_VPT];
  int s = 0;
#pragma unroll
  for (int j = 0; j < SCAN_VPT; ++j) {
    v[j] = (base + j < n) ? pos[base + j] : 0;
    s += v[j];
  }
  sdata[t] = s;
  __syncthreads();
  for (int off = 1; off < SCAN_BLK; off <<= 1) {
    int xv = (t >= off) ? sdata[t - off] : 0;
    __syncthreads();
    sdata[t] += xv;
    __syncthreads();
  }
  const int excl = sdata[t] - s;
  const int total = sdata[SCAN_BLK - 1];

  if (t == 0) {
    const unsigned long long st =
        ((unsigned long long)(b == 0 ? 2 : 1) << 62) | (unsigned int)total;
    __hip_atomic_store(&state[b], st, __ATOMIC_RELEASE, __HIP_MEMORY_SCOPE_AGENT);
  }

  if (b == 0) {
    if (t == 0) s_prefix = 0;
  } else if (t < 64) {
    int windowEnd = b;
    int acc = 0;
    for (;;) {
      const int j = windowEnd - 1 - t;
      unsigned long long st = 0;
      if (j >= 0) {
        do {
          st = __hip_atomic_load(&state[j], __ATOMIC_ACQUIRE, __HIP_MEMORY_SCOPE_AGENT);
        } while (st == 0);
      }
      const int flag = (j >= 0) ? (int)(st >> 62) : 2;
      const int val = (j >= 0) ? (int)(st & 0xffffffffull) : 0;
      const unsigned long long mask = __ballot(flag == 2);
      if (mask) {
        const int firstLane = __ffsll((long long)mask) - 1;
        int contrib = (t <= firstLane) ? val : 0;
#pragma unroll
        for (int o = 32; o > 0; o >>= 1) contrib += __shfl_down(contrib, o);
        if (t == 0) { acc += contrib; s_prefix = acc; }
        break;
      } else {
        int contrib = val;
#pragma unroll
        for (int o = 32; o > 0; o >>= 1) contrib += __shfl_down(contrib, o);
        if (t == 0) acc += contrib;
        windowEnd -= 64;
      }
    }
  }
  __syncthreads();
  const int add = s_prefix;

  if (t == 0 && b > 0) {
    const unsigned long long st = (2ull << 62) | (unsigned int)(add + total);
    __hip_atomic_store(&state[b], st, __ATOMIC_RELEASE, __HIP_MEMORY_SCOPE_AGENT);
  }

  int run = add + excl;
#pragma unroll
  for (int j = 0; j < SCAN_VPT; ++j) {
    if (base + j < n) {
      offsets[base + j] = run;
      pos[base + j] = run;
    }
    run += v[j];
  }
  if (b == 0 && t == 0) offsets[n] = n_edges;
}

// ---------------------------------------------------------------------------
// scatter: pairs[slot] = {src, bits(weight)} in dst-sorted order.
// ---------------------------------------------------------------------------
__global__ __launch_bounds__(256) void scatter_kernel(
    const int* __restrict__ esrc, const int* __restrict__ edst,
    const float* __restrict__ ew, int* __restrict__ pos,
    int2* __restrict__ pairs, int n_edges) {
  const int e = blockIdx.x * 256 + threadIdx.x;
  if (e >= n_edges) return;
  const int d = edst[e];
  const int slot = atomicAdd(&pos[d], 1);
  pairs[slot] = make_int2(esrc[e], __float_as_int(ew[e]));
}

// ---------------------------------------------------------------------------
// sage_agg: TWO nodes per wave over their CONTIGUOUS combined edge range
// (pairs is dst-sorted -> [off[n0], off[n0+2]) is one run). 8-deep batches =
// 16 gathers in flight per latency round; per-edge select (w0/w1, exact:
// fmaf(0,v,a)=a) routes into a0/a1 preserving per-node order. Out-row loads
// hoisted ahead of the dependent pair->gather chain. No LDS, no barriers.
// ---------------------------------------------------------------------------
__global__ __launch_bounds__(256) void sage_agg(
    const __hip_bfloat16* __restrict__ h,
    const int* __restrict__ offsets, const int2* __restrict__ pairs,
    float* __restrict__ out, int n_nodes) {
  const int wid = blockIdx.x * 4 + (threadIdx.x >> 6);
  const int node0 = wid * 2;
  if (node0 >= n_nodes) return;
  const int lane = threadIdx.x & 63;
  const bool two = (node0 + 1 < n_nodes);

  float2 a0 = *(const float2*)&out[(size_t)node0 * D + 2 * lane];
  float2 a1 = two ? *(const float2*)&out[(size_t)(node0 + 1) * D + 2 * lane]
                  : make_float2(0.f, 0.f);

  const int b0 = offsets[node0];
  const int e0 = offsets[node0 + 1];
  const int e1 = two ? offsets[node0 + 2] : e0;
  const __hip_bfloat162* __restrict__ h2 = (const __hip_bfloat162*)h;

  for (int i = b0; i < e1; i += 8) {
    int2 p[8];
    float wv[8];
#pragma unroll
    for (int u = 0; u < 8; ++u) {
      const int idx = i + u;
      const int ci = idx < e1 ? idx : e1 - 1;   // clamp (valid slot)
      p[u] = pairs[ci];
      wv[u] = (idx < e1) ? __int_as_float(p[u].y) : 0.f;
    }
    __hip_bfloat162 hv[8];
#pragma unroll
    for (int u = 0; u < 8; ++u)
      hv[u] = h2[(size_t)p[u].x * (D / 2) + lane];
#pragma unroll
    for (int u = 0; u < 8; ++u) {
      const bool to0 = (i + u) < e0;
      const float w0 = to0 ? wv[u] : 0.f;
      const float w1 = to0 ? 0.f : wv[u];
      const float hx = __bfloat162float(hv[u].x);
      const float hy = __bfloat162float(hv[u].y);
      a0.x = fmaf(w0, hx, a0.x);
      a0.y = fmaf(w0, hy, a0.y);
      a1.x = fmaf(w1, hx, a1.x);
      a1.y = fmaf(w1, hy, a1.y);
    }
  }

  *(float2*)&out[(size_t)node0 * D + 2 * lane] = a0;
  if (two) *(float2*)&out[(size_t)(node0 + 1) * D + 2 * lane] = a1;
}

// ---------------------------------------------------------------------------
extern "C" void kernel_launch(void* const* d_in, const int* in_sizes, int n_in,
                              void* d_out, int out_size, void* d_ws, size_t ws_size,
                              hipStream_t stream) {
  const float* x   = (const float*)d_in[0];
  const int* esrc  = (const int*)d_in[1];
  const int* edst  = (const int*)d_in[2];
  const float* ew  = (const float*)d_in[3];
  const float* Wl  = (const float*)d_in[4];
  const float* bl  = (const float*)d_in[5];
  const float* Wr  = (const float*)d_in[6];
  const float* br  = (const float*)d_in[7];
  float* out = (float*)d_out;

  const int n_nodes = in_sizes[0] / D;   // 100000
  const int n_edges = in_sizes[1];       // 600000

  // Workspace layout (16B aligned sections)
  char* ws = (char*)d_ws;
  size_t off = 0;
  __hip_bfloat16* h = (__hip_bfloat16*)(ws + off);      // 25.6 MB
  off += (size_t)n_nodes * D * sizeof(__hip_bfloat16);
  off = (off + 15) & ~15ull;
  int* offsets = (int*)(ws + off);
  off += (size_t)(n_nodes + 1) * sizeof(int);
  off = (off + 15) & ~15ull;
  int* pos = (int*)(ws + off);                          // degree, then cursors
  off += (size_t)n_nodes * sizeof(int);
  off = (off + 15) & ~15ull;
  unsigned long long* state = (unsigned long long*)(ws + off);  // lookback
  off += 1024 * sizeof(unsigned long long);
  off = (off + 15) & ~15ull;
  int2* pairs = (int2*)(ws + off);                      // 4.8 MB
  off += (size_t)n_edges * sizeof(int2);
  off = (off + 15) & ~15ull;
  __hip_bfloat16* WTl = (__hip_bfloat16*)(ws + off);
  off += (size_t)D * D * sizeof(__hip_bfloat16);
  __hip_bfloat16* WTr = (__hip_bfloat16*)(ws + off);
  off += (size_t)D * D * sizeof(__hip_bfloat16);
  float* bsum = (float*)(ws + off);
  off += D * sizeof(float);

  prep_w<<<128, 256, 0, stream>>>(Wl, Wr, bl, br, WTl, WTr, bsum, pos, state, n_nodes);

  const int n_tiles = (n_nodes + 15) / 16;              // 6250 (exact)
  const int gemm_blocks = (n_tiles + 3) / 4;            // 1563
  gemm_wt<<<gemm_blocks, 256, 0, stream>>>(x, WTl, WTr, bsum, h, out, edst, pos,
                                           n_edges, n_tiles);

  const int nparts = (n_nodes + SCAN_TILE - 1) / SCAN_TILE;   // 98
  scan_ll<<<nparts, SCAN_BLK, 0, stream>>>(pos, offsets, state, n_nodes, n_edges);

  scatter_kernel<<<(n_edges + 255) / 256, 256, 0, stream>>>(esrc, edst, ew, pos, pairs, n_edges);

  const int agg_blocks = (n_nodes / 2 + 3) / 4;         // 12500
  sage_agg<<<agg_blocks, 256, 0, stream>>>(h, offsets, pairs, out, n_nodes);
}

// Round 10
// 242.593 us; speedup vs baseline: 1.1016x; 1.1016x over previous
//
#include <hip/hip_runtime.h>
#include <hip/hip_bf16.h>

#define D 128
#define SCAN_BLK 256
#define SCAN_VPT 4
#define SCAN_TILE (SCAN_BLK * SCAN_VPT)   // 1024 nodes per scan block

typedef __attribute__((ext_vector_type(8))) short short8;   // 8 bf16 = 4 VGPR
typedef __attribute__((ext_vector_type(4))) float f32x4;    // MFMA C/D frag

// ---------------------------------------------------------------------------
// prep_w: WTl/WTr = bf16 transpose of Wl/Wr ([n][k] layout, 16B B-fragments);
// bsum = bl + br. Zeroes deg and the lookback state array.
// ---------------------------------------------------------------------------
__global__ __launch_bounds__(256) void prep_w(
    const float* __restrict__ Wl, const float* __restrict__ Wr,
    const float* __restrict__ bl, const float* __restrict__ br,
    __hip_bfloat16* __restrict__ WTl, __hip_bfloat16* __restrict__ WTr,
    float* __restrict__ bsum, int* __restrict__ deg,
    unsigned long long* __restrict__ state, int n_nodes) {
  const int tid = blockIdx.x * 256 + threadIdx.x;  // grid 128 -> 0..32767
  const int n = (tid >> 7) & 127;
  const int k = tid & 127;
  if (tid < 16384) {
    WTl[n * D + k] = __float2bfloat16(Wl[k * D + n]);
  } else {
    WTr[n * D + k] = __float2bfloat16(Wr[k * D + n]);
  }
  if (tid < 128) bsum[tid] = bl[tid] + br[tid];
  if (tid < 1024) state[tid] = 0ull;
  for (int i = tid; i < n_nodes; i += 32768) deg[i] = 0;
}

// ---------------------------------------------------------------------------
// gemm_hr: h = bf16(x @ Wl) AND out = x @ Wr + bsum. v6 block-tile structure
// (B-frags in registers, reused across grid-stride tiles) + T14 async-stage:
// next tile's x-loads issued into REGISTERS right after the staging barrier,
// so HBM latency hides under the current tile's MFMA + stores. The vmcnt
// wait lands at the next iteration's LDS-write, not at a drained barrier.
// Histogram prologue kept (atomics overlap other waves' work).
// ---------------------------------------------------------------------------
__global__ __launch_bounds__(256) void gemm_hr(
    const float* __restrict__ x, const __hip_bfloat16* __restrict__ WTl,
    const __hip_bfloat16* __restrict__ WTr, const float* __restrict__ bsum,
    __hip_bfloat16* __restrict__ h, float* __restrict__ out,
    const int* __restrict__ edst, int* __restrict__ deg, int n_edges,
    int n_rowtiles) {
  const int t = threadIdx.x;
  const int gsz = gridDim.x * 256;
  for (int e = blockIdx.x * 256 + t; e < n_edges; e += gsz)
    atomicAdd(&deg[edst[e]], 1);

  __shared__ __hip_bfloat16 xs[16][136];   // +8 pad
  const int wave = t >> 6;
  const int lane = t & 63;
  const int m = lane & 15;
  const int q = lane >> 4;

  // B fragments + bias: loaded once, reused for every tile (L2-hot tables)
  short8 bfl[2][4], bfr[2][4];
  float bias[2];
#pragma unroll
  for (int c = 0; c < 2; ++c) {
    const int n0 = wave * 32 + c * 16;
    bias[c] = bsum[n0 + m];
#pragma unroll
    for (int ks = 0; ks < 4; ++ks) {
      bfl[c][ks] = *(const short8*)&WTl[(n0 + m) * D + ks * 32 + q * 8];
      bfr[c][ks] = *(const short8*)&WTr[(n0 + m) * D + ks * 32 + q * 8];
    }
  }

  const int srow = t >> 4;
  const int scol = (t & 15) * 8;

  // prologue: load tile 0 into registers
  int rt = blockIdx.x;
  float4 pv0, pv1;
  if (rt < n_rowtiles) {
    const float4* src = (const float4*)&x[(size_t)(rt * 16 + srow) * D + scol];
    pv0 = src[0];
    pv1 = src[1];
  }

  for (; rt < n_rowtiles; rt += gridDim.x) {
    const int rowbase = rt * 16;

    // stage prefetched regs -> LDS (bf16 convert); vmcnt wait happens here
    {
      __hip_bfloat16* dst = &xs[srow][scol];
      dst[0] = __float2bfloat16(pv0.x); dst[1] = __float2bfloat16(pv0.y);
      dst[2] = __float2bfloat16(pv0.z); dst[3] = __float2bfloat16(pv0.w);
      dst[4] = __float2bfloat16(pv1.x); dst[5] = __float2bfloat16(pv1.y);
      dst[6] = __float2bfloat16(pv1.z); dst[7] = __float2bfloat16(pv1.w);
    }
    __syncthreads();

    // issue NEXT tile's loads now — they fly during MFMA + stores below
    const int nrt = rt + gridDim.x;
    if (nrt < n_rowtiles) {
      const float4* src = (const float4*)&x[(size_t)(nrt * 16 + srow) * D + scol];
      pv0 = src[0];
      pv1 = src[1];
    }

    f32x4 accL[2], accR[2];
#pragma unroll
    for (int c = 0; c < 2; ++c)
#pragma unroll
      for (int r = 0; r < 4; ++r) { accL[c][r] = 0.f; accR[c][r] = 0.f; }

#pragma unroll
    for (int ks = 0; ks < 4; ++ks) {
      const short8 afrag = *(const short8*)&xs[m][ks * 32 + q * 8];
#pragma unroll
      for (int c = 0; c < 2; ++c) {
        accL[c] = __builtin_amdgcn_mfma_f32_16x16x32_bf16(afrag, bfl[c][ks], accL[c], 0, 0, 0);
        accR[c] = __builtin_amdgcn_mfma_f32_16x16x32_bf16(afrag, bfr[c][ks], accR[c], 0, 0, 0);
      }
    }

#pragma unroll
    for (int c = 0; c < 2; ++c) {
      const int n = wave * 32 + c * 16 + m;
#pragma unroll
      for (int r = 0; r < 4; ++r) {
        const size_t row = (size_t)(rowbase + q * 4 + r);
        h[row * D + n] = __float2bfloat16(accL[c][r]);
        out[row * D + n] = accR[c][r] + bias[c];
      }
    }
    __syncthreads();   // all waves done reading xs before next stage
  }
}

// ---------------------------------------------------------------------------
// scan_ll: single-pass decoupled-lookback exclusive scan of deg -> offsets
// and pos cursors (proven round 8). 98 blocks <= CU count -> co-resident.
// ---------------------------------------------------------------------------
__global__ __launch_bounds__(SCAN_BLK) void scan_ll(
    int* __restrict__ pos /* deg in, cursors out */, int* __restrict__ offsets,
    unsigned long long* __restrict__ state, int n, int n_edges) {
  __shared__ int sdata[SCAN_BLK];
  __shared__ int s_prefix;
  const int t = threadIdx.x;
  const int b = blockIdx.x;
  const int base = b * SCAN_TILE + t * SCAN_VPT;

  int v[SCAN_VPT];
  int s = 0;
#pragma unroll
  for (int j = 0; j < SCAN_VPT; ++j) {
    v[j] = (base + j < n) ? pos[base + j] : 0;
    s += v[j];
  }
  sdata[t] = s;
  __syncthreads();
  for (int off = 1; off < SCAN_BLK; off <<= 1) {
    int xv = (t >= off) ? sdata[t - off] : 0;
    __syncthreads();
    sdata[t] += xv;
    __syncthreads();
  }
  const int excl = sdata[t] - s;
  const int total = sdata[SCAN_BLK - 1];

  if (t == 0) {
    const unsigned long long st =
        ((unsigned long long)(b == 0 ? 2 : 1) << 62) | (unsigned int)total;
    __hip_atomic_store(&state[b], st, __ATOMIC_RELEASE, __HIP_MEMORY_SCOPE_AGENT);
  }

  if (b == 0) {
    if (t == 0) s_prefix = 0;
  } else if (t < 64) {
    int windowEnd = b;
    int acc = 0;
    for (;;) {
      const int j = windowEnd - 1 - t;
      unsigned long long st = 0;
      if (j >= 0) {
        do {
          st = __hip_atomic_load(&state[j], __ATOMIC_ACQUIRE, __HIP_MEMORY_SCOPE_AGENT);
        } while (st == 0);
      }
      const int flag = (j >= 0) ? (int)(st >> 62) : 2;
      const int val = (j >= 0) ? (int)(st & 0xffffffffull) : 0;
      const unsigned long long mask = __ballot(flag == 2);
      if (mask) {
        const int firstLane = __ffsll((long long)mask) - 1;
        int contrib = (t <= firstLane) ? val : 0;
#pragma unroll
        for (int o = 32; o > 0; o >>= 1) contrib += __shfl_down(contrib, o);
        if (t == 0) { acc += contrib; s_prefix = acc; }
        break;
      } else {
        int contrib = val;
#pragma unroll
        for (int o = 32; o > 0; o >>= 1) contrib += __shfl_down(contrib, o);
        if (t == 0) acc += contrib;
        windowEnd -= 64;
      }
    }
  }
  __syncthreads();
  const int add = s_prefix;

  if (t == 0 && b > 0) {
    const unsigned long long st = (2ull << 62) | (unsigned int)(add + total);
    __hip_atomic_store(&state[b], st, __ATOMIC_RELEASE, __HIP_MEMORY_SCOPE_AGENT);
  }

  int run = add + excl;
#pragma unroll
  for (int j = 0; j < SCAN_VPT; ++j) {
    if (base + j < n) {
      offsets[base + j] = run;
      pos[base + j] = run;
    }
    run += v[j];
  }
  if (b == 0 && t == 0) offsets[n] = n_edges;
}

// ---------------------------------------------------------------------------
// scatter: pairs[slot] = {src, bits(weight)} in dst-sorted order.
// ---------------------------------------------------------------------------
__global__ __launch_bounds__(256) void scatter_kernel(
    const int* __restrict__ esrc, const int* __restrict__ edst,
    const float* __restrict__ ew, int* __restrict__ pos,
    int2* __restrict__ pairs, int n_edges) {
  const int e = blockIdx.x * 256 + threadIdx.x;
  if (e >= n_edges) return;
  const int d = edst[e];
  const int slot = atomicAdd(&pos[d], 1);
  pairs[slot] = make_int2(esrc[e], __float_as_int(ew[e]));
}

// ---------------------------------------------------------------------------
// sage_agg: pure gather-accumulate (v6, proven). One node per wave, no LDS,
// no barriers. a = out_row (root); masked 8-deep batch covers avg degree-6
// in one latency round (clamp + zero weight keeps exact accumulation order).
// ---------------------------------------------------------------------------
__global__ __launch_bounds__(256) void sage_agg(
    const __hip_bfloat16* __restrict__ h,
    const int* __restrict__ offsets, const int2* __restrict__ pairs,
    float* __restrict__ out, int n_nodes) {
  const int node = blockIdx.x * 4 + (threadIdx.x >> 6);
  const int lane = threadIdx.x & 63;
  if (node >= n_nodes) return;
  const int begin = offsets[node];
  const int end = offsets[node + 1];
  const __hip_bfloat162* __restrict__ h2 = (const __hip_bfloat162*)h;

  float2 a = *(const float2*)&out[(size_t)node * D + 2 * lane];

  int i = begin;
  for (; i + 8 <= end; i += 8) {
    int2 p[8];
#pragma unroll
    for (int u = 0; u < 8; ++u) p[u] = pairs[i + u];
    __hip_bfloat162 hv[8];
#pragma unroll
    for (int u = 0; u < 8; ++u)
      hv[u] = h2[(size_t)p[u].x * (D / 2) + lane];
#pragma unroll
    for (int u = 0; u < 8; ++u) {
      const float w = __int_as_float(p[u].y);
      a.x = fmaf(w, __bfloat162float(hv[u].x), a.x);
      a.y = fmaf(w, __bfloat162float(hv[u].y), a.y);
    }
  }
  if (i < end) {
    int2 p[8];
#pragma unroll
    for (int u = 0; u < 8; ++u) {
      const int ei = (i + u < end) ? (i + u) : (end - 1);   // clamp (valid)
      p[u] = pairs[ei];
      if (i + u >= end) p[u].y = 0;                         // w = 0.0f
    }
    __hip_bfloat162 hv[8];
#pragma unroll
    for (int u = 0; u < 8; ++u)
      hv[u] = h2[(size_t)p[u].x * (D / 2) + lane];
#pragma unroll
    for (int u = 0; u < 8; ++u) {
      const float w = __int_as_float(p[u].y);
      a.x = fmaf(w, __bfloat162float(hv[u].x), a.x);
      a.y = fmaf(w, __bfloat162float(hv[u].y), a.y);
    }
  }

  *(float2*)&out[(size_t)node * D + 2 * lane] = a;
}

// ---------------------------------------------------------------------------
extern "C" void kernel_launch(void* const* d_in, const int* in_sizes, int n_in,
                              void* d_out, int out_size, void* d_ws, size_t ws_size,
                              hipStream_t stream) {
  const float* x   = (const float*)d_in[0];
  const int* esrc  = (const int*)d_in[1];
  const int* edst  = (const int*)d_in[2];
  const float* ew  = (const float*)d_in[3];
  const float* Wl  = (const float*)d_in[4];
  const float* bl  = (const float*)d_in[5];
  const float* Wr  = (const float*)d_in[6];
  const float* br  = (const float*)d_in[7];
  float* out = (float*)d_out;

  const int n_nodes = in_sizes[0] / D;   // 100000
  const int n_edges = in_sizes[1];       // 600000

  // Workspace layout (16B aligned sections)
  char* ws = (char*)d_ws;
  size_t off = 0;
  __hip_bfloat16* h = (__hip_bfloat16*)(ws + off);      // 25.6 MB
  off += (size_t)n_nodes * D * sizeof(__hip_bfloat16);
  off = (off + 15) & ~15ull;
  int* offsets = (int*)(ws + off);
  off += (size_t)(n_nodes + 1) * sizeof(int);
  off = (off + 15) & ~15ull;
  int* pos = (int*)(ws + off);                          // degree, then cursors
  off += (size_t)n_nodes * sizeof(int);
  off = (off + 15) & ~15ull;
  unsigned long long* state = (unsigned long long*)(ws + off);  // lookback
  off += 1024 * sizeof(unsigned long long);
  off = (off + 15) & ~15ull;
  int2* pairs = (int2*)(ws + off);                      // 4.8 MB
  off += (size_t)n_edges * sizeof(int2);
  off = (off + 15) & ~15ull;
  __hip_bfloat16* WTl = (__hip_bfloat16*)(ws + off);
  off += (size_t)D * D * sizeof(__hip_bfloat16);
  __hip_bfloat16* WTr = (__hip_bfloat16*)(ws + off);
  off += (size_t)D * D * sizeof(__hip_bfloat16);
  float* bsum = (float*)(ws + off);
  off += D * sizeof(float);

  prep_w<<<128, 256, 0, stream>>>(Wl, Wr, bl, br, WTl, WTr, bsum, pos, state, n_nodes);

  const int n_rowtiles = (n_nodes + 15) / 16;           // 6250 (exact)
  const int gemm_grid = n_rowtiles < 2048 ? n_rowtiles : 2048;
  gemm_hr<<<gemm_grid, 256, 0, stream>>>(x, WTl, WTr, bsum, h, out, edst, pos,
                                         n_edges, n_rowtiles);

  const int nparts = (n_nodes + SCAN_TILE - 1) / SCAN_TILE;   // 98
  scan_ll<<<nparts, SCAN_BLK, 0, stream>>>(pos, offsets, state, n_nodes, n_edges);

  scatter_kernel<<<(n_edges + 255) / 256, 256, 0, stream>>>(esrc, edst, ew, pos, pairs, n_edges);

  sage_agg<<<(n_nodes + 3) / 4, 256, 0, stream>>>(h, offsets, pairs, out, n_nodes);
}